// Round 4
// baseline (247.117 us; speedup 1.0000x reference)
//
#include <hip/hip_runtime.h>

#define TPB 512
#define NW 8
#define NPTS 2000
#define M1C 100
#define M2C 5
#define KNN 20
#define CAP 64
#define CANDCAP 128

// workspace layout (float words), per cloud stride CSTR:
#define CSTR 4120
#define OF_SMPX 0
#define OF_SMPY 100
#define OF_SMPZ 200
#define OF_S2   300   // x[300..304] y[305..309] z[310..314]
#define OF_F1   320   // [s*5+f], 500 floats
#define OF_CNT  820   // 100 ints
#define OF_CANDI 920  // u16[100][64] = 3200 words

// Bitwise-exact squared distance matching numpy fp32 sequential sum:
// ((dx*dx + dy*dy) + dz*dz), no FMA contraction.
__device__ __forceinline__ float dist3(float px, float py, float pz,
                                       float qx, float qy, float qz) {
#pragma clang fp contract(off)
    float dx = px - qx, dy = py - qy, dz = pz - qz;
    return dx * dx + dy * dy + dz * dz;
}
__device__ __forceinline__ float dist3d(float px, float py, float pz,
                                        float qx, float qy, float qz,
                                        float& dx, float& dy, float& dz) {
#pragma clang fp contract(off)
    dx = px - qx; dy = py - qy; dz = pz - qz;
    return dx * dx + dy * dy + dz * dz;
}

// Fused wave64 (value,index) argmax, min-index tie-break, DPP chain.
#define ARGMAX_STEP(ctrl, rm)                                                        \
    do {                                                                             \
        float ov = __int_as_float(__builtin_amdgcn_update_dpp(                       \
            (int)0xff800000, __float_as_int(v), ctrl, rm, 0xf, false));              \
        int oi = __builtin_amdgcn_update_dpp(0x7fffffff, i, ctrl, rm, 0xf, false);   \
        bool take = (ov > v) || (ov == v && oi < i);                                 \
        v = take ? ov : v;                                                           \
        i = take ? oi : i;                                                           \
    } while (0)

__device__ __forceinline__ void wave_argmax(float& v, int& i) {
    ARGMAX_STEP(0x111, 0xf);
    ARGMAX_STEP(0x112, 0xf);
    ARGMAX_STEP(0x114, 0xf);
    ARGMAX_STEP(0x118, 0xf);
    ARGMAX_STEP(0x142, 0xa);
    ARGMAX_STEP(0x143, 0xc);
    v = __int_as_float(__builtin_amdgcn_readlane(__float_as_int(v), 63));
    i = __builtin_amdgcn_readlane(i, 63);
}

#define FMAX_STEP(ctrl, rm)                                                          \
    do {                                                                             \
        float _t = __int_as_float(__builtin_amdgcn_update_dpp(                       \
            (int)0xff800000, __float_as_int(x), ctrl, rm, 0xf, false));              \
        x = fmaxf(x, _t);                                                            \
    } while (0)

__device__ __forceinline__ float wave_fmax(float x) {
    FMAX_STEP(0x111, 0xf);
    FMAX_STEP(0x112, 0xf);
    FMAX_STEP(0x114, 0xf);
    FMAX_STEP(0x118, 0xf);
    FMAX_STEP(0x142, 0xa);
    FMAX_STEP(0x143, 0xc);
    return __int_as_float(__builtin_amdgcn_readlane(__float_as_int(x), 63));
}

// ============================ Kernel A: FPS ============================
__global__ __launch_bounds__(TPB) void kernelA(const float* __restrict__ P,
                                               float* __restrict__ ws)
{
    __shared__ float sP[3][NPTS];
    __shared__ unsigned short candi16[M1C * CAP];
    __shared__ int cnt[M1C];
    __shared__ float smpx[M1C], smpy[M1C], smpz[M1C];
    __shared__ __align__(16) float4 sA[2][NW];
    __shared__ __align__(16) float sZ[2][NW];

    const int b = blockIdx.x;
    const int tid = threadIdx.x;
    const int lane = tid & 63;
    const int wid = tid >> 6;
    float* sx = sP[0]; float* sy = sP[1]; float* sz = sP[2];
    const float R1SQ = (float)(0.3 * 0.3);   // f64 product then cast

    const float* Pb = P + (size_t)b * (NPTS * 3);
    const float4* P4 = (const float4*)Pb;
    for (int i = tid; i < (NPTS * 3) / 4; i += TPB) {
        float4 f = P4[i];
        int j = 4 * i;
        float v[4] = {f.x, f.y, f.z, f.w};
#pragma unroll
        for (int e = 0; e < 4; ++e) {
            int jj = j + e;
            (&sP[0][0])[(jj % 3) * NPTS + jj / 3] = v[e];
        }
    }
    for (int t = tid; t < M1C; t += TPB) cnt[t] = 0;
    __syncthreads();

    float px[4], py[4], pz[4], mind[4];
#pragma unroll
    for (int k = 0; k < 4; ++k) {
        int j = tid + (k << 9);
        bool v = j < NPTS;
        int jc = v ? j : 0;
        px[k] = v ? sx[jc] : 1e18f;
        py[k] = v ? sy[jc] : 1e18f;
        pz[k] = v ? sz[jc] : 1e18f;
        mind[k] = v ? 1e10f : -1.0f;
    }

    float qx = sx[0], qy = sy[0], qz = sz[0];
    for (int it = 0; it < M1C; ++it) {
        if (tid == 0) { smpx[it] = qx; smpy[it] = qy; smpz[it] = qz; }
        float bv = -1.0f; int bi = 0x7fffffff;
#pragma unroll
        for (int k = 0; k < 4; ++k) {
            int j = tid + (k << 9);
            float dx, dy, dz;
            float d = dist3d(px[k], py[k], pz[k], qx, qy, qz, dx, dy, dz);
            float m = fminf(mind[k], d);
            mind[k] = m;
            if (m > bv) { bv = m; bi = j; }     // strict >: min-idx ties
            if (d <= R1SQ) {
                int pos = atomicAdd(&cnt[it], 1);
                if (pos < CAP) candi16[it * CAP + pos] = (unsigned short)j;
            }
        }
        if (it == M1C - 1) break;
        float lv = bv; int li = bi;
        wave_argmax(bv, bi);
        int p = it & 1;
        if (lv == bv && li == bi) {            // exactly one lane: the winner
            int k = bi >> 9;                   // its own chunk of the winner
            float cx = k == 0 ? px[0] : k == 1 ? px[1] : k == 2 ? px[2] : px[3];
            float cy = k == 0 ? py[0] : k == 1 ? py[1] : k == 2 ? py[2] : py[3];
            float cz = k == 0 ? pz[0] : k == 1 ? pz[1] : k == 2 ? pz[2] : pz[3];
            sA[p][wid] = make_float4(bv, __int_as_float(bi), cx, cy);
            sZ[p][wid] = cz;
        }
        __syncthreads();
        float4 a0 = sA[p][0], a1 = sA[p][1], a2 = sA[p][2], a3 = sA[p][3];
        float4 a4 = sA[p][4], a5 = sA[p][5], a6 = sA[p][6], a7 = sA[p][7];
        float4 z0 = *(const float4*)&sZ[p][0];
        float4 z1 = *(const float4*)&sZ[p][4];
        float cv = a0.x; int ci = __float_as_int(a0.y);
        qx = a0.z; qy = a0.w; qz = z0.x;
#define SEL(aw, zz)                                                                  \
        {                                                                            \
            int ii = __float_as_int(aw.y);                                           \
            bool t = (aw.x > cv) || (aw.x == cv && ii < ci);                         \
            if (t) { cv = aw.x; ci = ii; qx = aw.z; qy = aw.w; qz = zz; }            \
        }
        SEL(a1, z0.y) SEL(a2, z0.z) SEL(a3, z0.w)
        SEL(a4, z1.x) SEL(a5, z1.y) SEL(a6, z1.z) SEL(a7, z1.w)
#undef SEL
    }
    __syncthreads();

    size_t cs = (size_t)b * CSTR;
    if (wid == 0) {
        // FPS2: 5 from 100; write s2 coords straight to ws
        float ax = smpx[lane], ay = smpy[lane], az = smpz[lane];
        bool vb2 = lane < (M1C - 64);
        float bx2 = vb2 ? smpx[lane + 64] : 1e18f;
        float by2 = vb2 ? smpy[lane + 64] : 1e18f;
        float bz2 = vb2 ? smpz[lane + 64] : 1e18f;
        float m2a = 1e10f;
        float m2b = vb2 ? 1e10f : -1.0f;
        int last2 = 0;
        for (int it = 0; it < M2C; ++it) {
            float fx = smpx[last2], fy = smpy[last2], fz = smpz[last2];
            if (lane == 0) {
                ws[cs + OF_S2 + it] = fx;
                ws[cs + OF_S2 + 5 + it] = fy;
                ws[cs + OF_S2 + 10 + it] = fz;
            }
            m2a = fminf(m2a, dist3(ax, ay, az, fx, fy, fz));
            m2b = fminf(m2b, dist3(bx2, by2, bz2, fx, fy, fz));
            float v = m2a; int i = lane;
            if (m2b > v) { v = m2b; i = lane + 64; }
            wave_argmax(v, i);
            last2 = i;
        }
    } else {
        int t2 = tid - 64;
        for (int t = t2; t < M1C; t += TPB - 64) {
            ws[cs + OF_SMPX + t] = smpx[t];
            ws[cs + OF_SMPY + t] = smpy[t];
            ws[cs + OF_SMPZ + t] = smpz[t];
            ((int*)ws)[cs + OF_CNT + t] = cnt[t];
        }
        const unsigned* ca = (const unsigned*)candi16;
        unsigned* wsu = (unsigned*)ws;
        for (int t = t2; t < M1C * CAP / 2; t += TPB - 64)
            wsu[cs + OF_CANDI + t] = ca[t];
    }
}

// ===================== Kernel B: MLP1 per (cloud,sample) =====================
__global__ __launch_bounds__(TPB) void kernelB(const float* __restrict__ P,
                                               const float* __restrict__ W1,
                                               const float* __restrict__ b1,
                                               float* __restrict__ ws, int nPairs)
{
    __shared__ float cdw[NW][CANDCAP];
    __shared__ int ciw[NW][CANDCAP];
    const int tid = threadIdx.x;
    const int lane = tid & 63;
    const int wid = tid >> 6;
    int id = blockIdx.x * NW + wid;
    if (id >= nPairs) return;
    int cloud = id / M1C;
    int s = id - cloud * M1C;
    size_t cs = (size_t)cloud * CSTR;
    const float* Pc = P + (size_t)cloud * (NPTS * 3);
    const float R1SQ = (float)(0.3 * 0.3);
    const float INVR1 = 1.0f / 0.3f;

    float qx = ws[cs + OF_SMPX + s];
    float qy = ws[cs + OF_SMPY + s];
    float qz = ws[cs + OF_SMPZ + s];
    int cn = ((const int*)ws)[cs + OF_CNT + s];
    float rw1[15], rb1[5];
#pragma unroll
    for (int i = 0; i < 15; ++i) rw1[i] = W1[i];
#pragma unroll
    for (int i = 0; i < 5; ++i) rb1[i] = b1[i];
    float fmx[5];
#pragma unroll
    for (int f = 0; f < 5; ++f) fmx[f] = -1e30f;

    if (cn <= CAP) {
        const unsigned short* ci16 = (const unsigned short*)(ws + cs + OF_CANDI);
        int j = 0; float d = 0.0f;
        bool act = lane < cn;
        if (act) {
            j = ci16[s * CAP + lane];
            d = dist3(Pc[3 * j], Pc[3 * j + 1], Pc[3 * j + 2], qx, qy, qz);
            cdw[wid][lane] = d; ciw[wid][lane] = j;
        }
        if (act) {
            bool valid = true;
            if (cn > KNN) {
                int rank = 0;
                for (int u = 0; u < cn; ++u) {
                    float du = cdw[wid][u]; int iu = ciw[wid][u];
                    rank += (du < d || (du == d && iu < j)) ? 1 : 0;
                }
                valid = rank < KNN;   // replicates top_k stability (ties -> lower idx)
            }
            if (valid) {
                float rx = (Pc[3 * j] - qx) * INVR1;
                float ry = (Pc[3 * j + 1] - qy) * INVR1;
                float rz = (Pc[3 * j + 2] - qz) * INVR1;
#pragma unroll
                for (int f = 0; f < 5; ++f) {
                    float h = fmaf(rx, rw1[f], fmaf(ry, rw1[5 + f], fmaf(rz, rw1[10 + f], rb1[f])));
                    fmx[f] = fmaxf(fmx[f], fmaxf(h, 0.0f));
                }
            }
        }
    } else {
        // overflow fallback (statistically never): full rescan of the cloud
        int cn2 = 0;
        for (int c = 0; c < 32; ++c) {
            int j2 = c * 64 + lane;
            float d2 = 0.0f; bool pred = false;
            if (j2 < NPTS) {
                d2 = dist3(Pc[3 * j2], Pc[3 * j2 + 1], Pc[3 * j2 + 2], qx, qy, qz);
                pred = (d2 <= R1SQ);
            }
            unsigned long long mb = __ballot(pred);
            if (pred) {
                int pos = cn2 + (int)__popcll(mb & ((1ull << lane) - 1ull));
                if (pos < CANDCAP) { cdw[wid][pos] = d2; ciw[wid][pos] = j2; }
            }
            cn2 += (int)__popcll(mb);
        }
        if (cn2 > CANDCAP) cn2 = CANDCAP;
        for (int t = lane; t < cn2; t += 64) {
            float d = cdw[wid][t]; int j = ciw[wid][t];
            int rank = 0;
            for (int u = 0; u < cn2; ++u) {
                float du = cdw[wid][u]; int iu = ciw[wid][u];
                rank += (du < d || (du == d && iu < j)) ? 1 : 0;
            }
            if (rank < KNN) {
                float rx = (Pc[3 * j] - qx) * INVR1;
                float ry = (Pc[3 * j + 1] - qy) * INVR1;
                float rz = (Pc[3 * j + 2] - qz) * INVR1;
#pragma unroll
                for (int f = 0; f < 5; ++f) {
                    float h = fmaf(rx, rw1[f], fmaf(ry, rw1[5 + f], fmaf(rz, rw1[10 + f], rb1[f])));
                    fmx[f] = fmaxf(fmx[f], fmaxf(h, 0.0f));
                }
            }
        }
    }
#pragma unroll
    for (int f = 0; f < 5; ++f) fmx[f] = wave_fmax(fmx[f]);
    if (lane == 0) {
#pragma unroll
        for (int f = 0; f < 5; ++f) ws[cs + OF_F1 + s * 5 + f] = fmx[f];
    }
}

// ============== Kernel C: knn2 + MLP2 + MLP3 + decoder ==============
__global__ __launch_bounds__(TPB) void kernelC(
    const float* __restrict__ W2, const float* __restrict__ b2,
    const float* __restrict__ W3, const float* __restrict__ b3,
    const float* __restrict__ D1, const float* __restrict__ bD1,
    const float* __restrict__ D2, const float* __restrict__ bD2,
    const float* __restrict__ D3, const float* __restrict__ bD3,
    const float* __restrict__ ws, float* __restrict__ out)
{
    __shared__ float smpx[M1C], smpy[M1C], smpz[M1C];
    __shared__ float s2x[M2C], s2y[M2C], s2z[M2C];
    __shared__ float f1s[M1C][5];
    __shared__ float f2s[M2C][25];
    __shared__ float latent[45];
    __shared__ float decv[M2C][3];
    __shared__ float cfs[M2C][25];
    __shared__ float dec2s[M1C][3];
    __shared__ float cf2s[M1C][5];
    __shared__ float kn2d[NW][CANDCAP];
    __shared__ int   kn2i[NW][CANDCAP];
    __shared__ float w2s[200], b2s[25], w3s[1260], b3s[45];

    const int b = blockIdx.x;
    const int tid = threadIdx.x;
    const int lane = tid & 63;
    const int wid = tid >> 6;
    size_t cs = (size_t)b * CSTR;
    const float R2SQ = 1.0f;

    for (int t = tid; t < M1C; t += TPB) {
        smpx[t] = ws[cs + OF_SMPX + t];
        smpy[t] = ws[cs + OF_SMPY + t];
        smpz[t] = ws[cs + OF_SMPZ + t];
    }
    for (int t = tid; t < M2C; t += TPB) {
        s2x[t] = ws[cs + OF_S2 + t];
        s2y[t] = ws[cs + OF_S2 + 5 + t];
        s2z[t] = ws[cs + OF_S2 + 10 + t];
    }
    for (int t = tid; t < M1C * 5; t += TPB) ((float*)f1s)[t] = ws[cs + OF_F1 + t];
    for (int t = tid; t < 200; t += TPB) w2s[t] = W2[t];
    for (int t = tid; t < 25; t += TPB) b2s[t] = b2[t];
    for (int t = tid; t < 1260; t += TPB) w3s[t] = W3[t];
    for (int t = tid; t < 45; t += TPB) b3s[t] = b3[t];
    __syncthreads();

    // ---- knn2 + MLP2 -> f2 (one wave per sample2) ----
    for (int s = wid; s < M2C; s += NW) {
        float qx2 = s2x[s], qy2 = s2y[s], qz2 = s2z[s];
        int cn = 0;
#pragma unroll
        for (int c = 0; c < 2; ++c) {
            int j = c * 64 + lane;
            float d = 0.0f; bool pred = false;
            if (j < M1C) {
                d = dist3(smpx[j], smpy[j], smpz[j], qx2, qy2, qz2);
                pred = (d <= R2SQ);
            }
            unsigned long long mb = __ballot(pred);
            if (pred) {
                int pos = cn + (int)__popcll(mb & ((1ull << lane) - 1ull));
                kn2d[wid][pos] = d; kn2i[wid][pos] = j;   // cn<=100<CANDCAP
            }
            cn += (int)__popcll(mb);
        }
        float hmx[25];
#pragma unroll
        for (int f = 0; f < 25; ++f) hmx[f] = -1e30f;
        for (int t = lane; t < cn; t += 64) {
            float d = kn2d[wid][t]; int j = kn2i[wid][t];
            bool valid = true;
            if (cn > KNN) {
                int rank = 0;
                for (int u = 0; u < cn; ++u) {
                    float du = kn2d[wid][u]; int iu = kn2i[wid][u];
                    rank += (du < d || (du == d && iu < j)) ? 1 : 0;
                }
                valid = rank < KNN;
            }
            if (valid) {
                float in8[8];
                in8[0] = smpx[j] - qx2; in8[1] = smpy[j] - qy2; in8[2] = smpz[j] - qz2;
#pragma unroll
                for (int f = 0; f < 5; ++f) in8[3 + f] = f1s[j][f];
#pragma unroll
                for (int f = 0; f < 25; ++f) {
                    float h = b2s[f];
#pragma unroll
                    for (int i = 0; i < 8; ++i) h = fmaf(in8[i], w2s[i * 25 + f], h);
                    hmx[f] = fmaxf(hmx[f], fmaxf(h, 0.0f));
                }
            }
        }
#pragma unroll
        for (int f = 0; f < 25; ++f) {
            float mx = wave_fmax(hmx[f]);
            if (lane == 0) f2s[s][f] = mx;
        }
    }
    __syncthreads();

    // ---- MLP3 + max-pool -> latent (45) ----
    if (wid == 0 && lane < 45) {
        float lm = -1e30f;
        for (int r = 0; r < M2C; ++r) {
            float h = b3s[lane];
            h = fmaf(s2x[r] * 0.5f, w3s[0 * 45 + lane], h);
            h = fmaf(s2y[r] * 0.5f, w3s[1 * 45 + lane], h);
            h = fmaf(s2z[r] * 0.5f, w3s[2 * 45 + lane], h);
#pragma unroll
            for (int i = 0; i < 25; ++i) h = fmaf(f2s[r][i], w3s[(3 + i) * 45 + lane], h);
            lm = fmaxf(lm, fmaxf(h, 0.0f));
        }
        latent[lane] = lm;
    }
    __syncthreads();

    // ---- decoder stage 1: latent @ D1 + bD1 -> (5, 28) ----
    for (int t = tid; t < 140; t += TPB) {
        float acc = bD1[t];
        for (int i = 0; i < 45; i++) acc = fmaf(latent[i], D1[i * 140 + t], acc);
        int r = t / 28, c = t % 28;
        if (c < 3) decv[r][c] = acc;
        else cfs[r][c - 3] = fmaxf(acc, 0.0f);
    }
    __syncthreads();

    // ---- decoder stage 2: cf @ D2 + bD2 -> (100, 8) ----
    for (int t = tid; t < 800; t += TPB) {
        int r = t / 160, c = t % 160;
        float acc = bD2[c];
        for (int i = 0; i < 25; i++) acc = fmaf(cfs[r][i], D2[i * 160 + c], acc);
        int g = r * 20 + c / 8, c8 = c % 8;
        if (c8 < 3) dec2s[g][c8] = acc;
        else cf2s[g][c8 - 3] = fmaxf(acc, 0.0f);
    }
    __syncthreads();

    // ---- decoder stage 3 + compose output ----
    float* outb = out + (size_t)b * (NPTS * 3);
    for (int t = tid; t < NPTS * 3; t += TPB) {
        int n = t / 3, c = t % 3;
        int g = n / 20;
        int m = n / 400;
        int r60 = (n % 20) * 3 + c;
        float acc = bD3[r60];
        for (int i = 0; i < 5; i++) acc = fmaf(cf2s[g][i], D3[i * 60 + r60], acc);
        // out = ((dec*R3 + dec2)*R2 + dec3)*R1, R2 = 1
        float val = ((decv[m][c] * 2.0f + dec2s[g][c]) + acc) * 0.3f;
        outb[t] = val;
    }
}

extern "C" void kernel_launch(void* const* d_in, const int* in_sizes, int n_in,
                              void* d_out, int out_size, void* d_ws, size_t ws_size,
                              hipStream_t stream) {
    const float* P   = (const float*)d_in[0];
    const float* W1  = (const float*)d_in[1];
    const float* b1  = (const float*)d_in[2];
    const float* W2  = (const float*)d_in[3];
    const float* b2  = (const float*)d_in[4];
    const float* W3  = (const float*)d_in[5];
    const float* b3  = (const float*)d_in[6];
    const float* D1  = (const float*)d_in[7];
    const float* bD1 = (const float*)d_in[8];
    const float* D2  = (const float*)d_in[9];
    const float* bD2 = (const float*)d_in[10];
    const float* D3  = (const float*)d_in[11];
    const float* bD3 = (const float*)d_in[12];
    float* out = (float*)d_out;
    float* ws = (float*)d_ws;

    int B = in_sizes[0] / (NPTS * 3);
    int nPairs = B * M1C;
    hipLaunchKernelGGL(kernelA, dim3(B), dim3(TPB), 0, stream, P, ws);
    hipLaunchKernelGGL(kernelB, dim3((nPairs + NW - 1) / NW), dim3(TPB), 0, stream,
                       P, W1, b1, ws, nPairs);
    hipLaunchKernelGGL(kernelC, dim3(B), dim3(TPB), 0, stream,
                       W2, b2, W3, b3, D1, bD1, D2, bD2, D3, bD3, ws, out);
}

// Round 5
// 237.280 us; speedup vs baseline: 1.0415x; 1.0415x over previous
//
#include <hip/hip_runtime.h>

#define TPB 512
#define NW 8
#define TPBA 256
#define NWA 4
#define NPTS 2000
#define M1C 100
#define M2C 5
#define KNN 20
#define CANDCAP 128

// workspace layout (float words), per cloud stride CSTR:
#define CSTR 320
#define OF_SMPX 0
#define OF_SMPY 100
#define OF_SMPZ 200
#define OF_S2   300   // x[300..304] y[305..309] z[310..314]

// Bitwise-exact squared distance matching numpy fp32 sequential sum:
// ((dx*dx + dy*dy) + dz*dz), no FMA contraction.
__device__ __forceinline__ float dist3(float px, float py, float pz,
                                       float qx, float qy, float qz) {
#pragma clang fp contract(off)
    float dx = px - qx, dy = py - qy, dz = pz - qz;
    return dx * dx + dy * dy + dz * dz;
}

// Fused wave64 (value,index) argmax, min-index tie-break, DPP chain.
#define ARGMAX_STEP(ctrl, rm)                                                        \
    do {                                                                             \
        float ov = __int_as_float(__builtin_amdgcn_update_dpp(                       \
            (int)0xff800000, __float_as_int(v), ctrl, rm, 0xf, false));              \
        int oi = __builtin_amdgcn_update_dpp(0x7fffffff, i, ctrl, rm, 0xf, false);   \
        bool take = (ov > v) || (ov == v && oi < i);                                 \
        v = take ? ov : v;                                                           \
        i = take ? oi : i;                                                           \
    } while (0)

__device__ __forceinline__ void wave_argmax(float& v, int& i) {
    ARGMAX_STEP(0x111, 0xf);
    ARGMAX_STEP(0x112, 0xf);
    ARGMAX_STEP(0x114, 0xf);
    ARGMAX_STEP(0x118, 0xf);
    ARGMAX_STEP(0x142, 0xa);
    ARGMAX_STEP(0x143, 0xc);
    v = __int_as_float(__builtin_amdgcn_readlane(__float_as_int(v), 63));
    i = __builtin_amdgcn_readlane(i, 63);
}

#define FMAX_STEP(ctrl, rm)                                                          \
    do {                                                                             \
        float _t = __int_as_float(__builtin_amdgcn_update_dpp(                       \
            (int)0xff800000, __float_as_int(x), ctrl, rm, 0xf, false));              \
        x = fmaxf(x, _t);                                                            \
    } while (0)

__device__ __forceinline__ float wave_fmax(float x) {
    FMAX_STEP(0x111, 0xf);
    FMAX_STEP(0x112, 0xf);
    FMAX_STEP(0x114, 0xf);
    FMAX_STEP(0x118, 0xf);
    FMAX_STEP(0x142, 0xa);
    FMAX_STEP(0x143, 0xc);
    return __int_as_float(__builtin_amdgcn_readlane(__float_as_int(x), 63));
}

// ==================== Kernel A: pure FPS (no recording) ====================
__global__ __launch_bounds__(TPBA) void kernelA(const float* __restrict__ P,
                                                float* __restrict__ ws)
{
    __shared__ float sP[3][NPTS];
    __shared__ float smpx[M1C], smpy[M1C], smpz[M1C];
    __shared__ __align__(16) float4 sA[2][NWA];
    __shared__ __align__(16) float sZ[2][NWA];

    const int b = blockIdx.x;
    const int tid = threadIdx.x;
    const int lane = tid & 63;
    const int wid = tid >> 6;
    float* sx = sP[0]; float* sy = sP[1]; float* sz = sP[2];

    const float* Pb = P + (size_t)b * (NPTS * 3);
    const float4* P4 = (const float4*)Pb;
    for (int i = tid; i < (NPTS * 3) / 4; i += TPBA) {
        float4 f = P4[i];
        int j = 4 * i;
        float v[4] = {f.x, f.y, f.z, f.w};
#pragma unroll
        for (int e = 0; e < 4; ++e) {
            int jj = j + e;
            (&sP[0][0])[(jj % 3) * NPTS + jj / 3] = v[e];
        }
    }
    __syncthreads();

    // points into registers: 8 chunks of 256
    float px[8], py[8], pz[8], mind[8];
#pragma unroll
    for (int k = 0; k < 8; ++k) {
        int j = tid + (k << 8);
        bool v = j < NPTS;
        int jc = v ? j : 0;
        px[k] = v ? sx[jc] : 1e18f;
        py[k] = v ? sy[jc] : 1e18f;
        pz[k] = v ? sz[jc] : 1e18f;
        mind[k] = v ? 1e10f : -1.0f;
    }

    float qx = sx[0], qy = sy[0], qz = sz[0];
    for (int it = 0; it < M1C; ++it) {
        if (tid == 0) { smpx[it] = qx; smpy[it] = qy; smpz[it] = qz; }
        float bv = -1.0f; int bi = 0x7fffffff;
#pragma unroll
        for (int k = 0; k < 8; ++k) {
            float d = dist3(px[k], py[k], pz[k], qx, qy, qz);
            float m = fminf(mind[k], d);
            mind[k] = m;
            if (m > bv) { bv = m; bi = tid + (k << 8); }   // strict >: min-idx ties
        }
        if (it == M1C - 1) break;
        float lv = bv; int li = bi;
        wave_argmax(bv, bi);
        int p = it & 1;
        if (lv == bv && li == bi) {            // unique winner lane per wave
            int k = bi >> 8;
            float cx = px[0], cy = py[0], cz = pz[0];
#pragma unroll
            for (int kk = 1; kk < 8; ++kk) {
                bool t = (k == kk);
                cx = t ? px[kk] : cx;
                cy = t ? py[kk] : cy;
                cz = t ? pz[kk] : cz;
            }
            sA[p][wid] = make_float4(bv, __int_as_float(bi), cx, cy);
            sZ[p][wid] = cz;
        }
        __syncthreads();
        float4 a0 = sA[p][0], a1 = sA[p][1], a2 = sA[p][2], a3 = sA[p][3];
        float4 z0 = *(const float4*)&sZ[p][0];
        float cv = a0.x; int ci = __float_as_int(a0.y);
        qx = a0.z; qy = a0.w; qz = z0.x;
#define SEL(aw, zz)                                                                  \
        {                                                                            \
            int ii = __float_as_int(aw.y);                                           \
            bool t = (aw.x > cv) || (aw.x == cv && ii < ci);                         \
            if (t) { cv = aw.x; ci = ii; qx = aw.z; qy = aw.w; qz = zz; }            \
        }
        SEL(a1, z0.y) SEL(a2, z0.z) SEL(a3, z0.w)
#undef SEL
    }
    __syncthreads();

    size_t cs = (size_t)b * CSTR;
    if (wid == 0) {
        // FPS2: 5 from 100; write s2 coords straight to ws
        float ax = smpx[lane], ay = smpy[lane], az = smpz[lane];
        bool vb2 = lane < (M1C - 64);
        float bx2 = vb2 ? smpx[lane + 64] : 1e18f;
        float by2 = vb2 ? smpy[lane + 64] : 1e18f;
        float bz2 = vb2 ? smpz[lane + 64] : 1e18f;
        float m2a = 1e10f;
        float m2b = vb2 ? 1e10f : -1.0f;
        int last2 = 0;
        for (int it = 0; it < M2C; ++it) {
            float fx = smpx[last2], fy = smpy[last2], fz = smpz[last2];
            if (lane == 0) {
                ws[cs + OF_S2 + it] = fx;
                ws[cs + OF_S2 + 5 + it] = fy;
                ws[cs + OF_S2 + 10 + it] = fz;
            }
            m2a = fminf(m2a, dist3(ax, ay, az, fx, fy, fz));
            m2b = fminf(m2b, dist3(bx2, by2, bz2, fx, fy, fz));
            float v = m2a; int i = lane;
            if (m2b > v) { v = m2b; i = lane + 64; }
            wave_argmax(v, i);
            last2 = i;
        }
    } else {
        int t2 = tid - 64;
        for (int t = t2; t < M1C; t += TPBA - 64) {
            ws[cs + OF_SMPX + t] = smpx[t];
            ws[cs + OF_SMPY + t] = smpy[t];
            ws[cs + OF_SMPZ + t] = smpz[t];
        }
    }
}

// ======== Kernel BC: knn1+MLP1, knn2+MLP2, MLP3, decoder (per cloud) ========
__global__ __launch_bounds__(TPB) void kernelBC(
    const float* __restrict__ P,
    const float* __restrict__ W1, const float* __restrict__ b1,
    const float* __restrict__ W2, const float* __restrict__ b2,
    const float* __restrict__ W3, const float* __restrict__ b3,
    const float* __restrict__ D1, const float* __restrict__ bD1,
    const float* __restrict__ D2, const float* __restrict__ bD2,
    const float* __restrict__ D3, const float* __restrict__ bD3,
    const float* __restrict__ ws, float* __restrict__ out)
{
    __shared__ float sP[3][NPTS];
    __shared__ float smpx[M1C], smpy[M1C], smpz[M1C];
    __shared__ float s2x[M2C], s2y[M2C], s2z[M2C];
    __shared__ float f1s[M1C][5];
    __shared__ float f2s[M2C][25];
    __shared__ float latent[45];
    __shared__ float decv[M2C][3];
    __shared__ float cfs[M2C][25];
    __shared__ float dec2s[M1C][3];
    __shared__ float cf2s[M1C][5];
    __shared__ float knd[NW][CANDCAP];
    __shared__ int   kni[NW][CANDCAP];
    __shared__ float w2s[200], b2s[25], w3s[1260], b3s[45];

    const int b = blockIdx.x;
    const int tid = threadIdx.x;
    const int lane = tid & 63;
    const int wid = tid >> 6;
    float* sx = sP[0]; float* sy = sP[1]; float* sz = sP[2];
    size_t cs = (size_t)b * CSTR;

    const float R1SQ = (float)(0.3 * 0.3);   // f64 product then cast
    const float R2SQ = 1.0f;
    const float INVR1 = 1.0f / 0.3f;

    const float* Pb = P + (size_t)b * (NPTS * 3);
    const float4* P4 = (const float4*)Pb;
    for (int i = tid; i < (NPTS * 3) / 4; i += TPB) {
        float4 f = P4[i];
        int j = 4 * i;
        float v[4] = {f.x, f.y, f.z, f.w};
#pragma unroll
        for (int e = 0; e < 4; ++e) {
            int jj = j + e;
            (&sP[0][0])[(jj % 3) * NPTS + jj / 3] = v[e];
        }
    }
    for (int t = tid; t < M1C; t += TPB) {
        smpx[t] = ws[cs + OF_SMPX + t];
        smpy[t] = ws[cs + OF_SMPY + t];
        smpz[t] = ws[cs + OF_SMPZ + t];
    }
    for (int t = tid; t < M2C; t += TPB) {
        s2x[t] = ws[cs + OF_S2 + t];
        s2y[t] = ws[cs + OF_S2 + 5 + t];
        s2z[t] = ws[cs + OF_S2 + 10 + t];
    }
    for (int t = tid; t < 200; t += TPB) w2s[t] = W2[t];
    for (int t = tid; t < 25; t += TPB) b2s[t] = b2[t];
    for (int t = tid; t < 1260; t += TPB) w3s[t] = W3[t];
    for (int t = tid; t < 45; t += TPB) b3s[t] = b3[t];
    float rw1[15], rb1[5];
#pragma unroll
    for (int i = 0; i < 15; ++i) rw1[i] = W1[i];
#pragma unroll
    for (int i = 0; i < 5; ++i) rb1[i] = b1[i];
    __syncthreads();

    // ---- knn1 + MLP1 -> f1 (one wave per sample, 8 waves round-robin) ----
    for (int s = wid; s < M1C; s += NW) {
        float qx = smpx[s], qy = smpy[s], qz = smpz[s];
        int cn = 0;
#pragma unroll 4
        for (int c = 0; c < 32; ++c) {
            int j = c * 64 + lane;
            float d = 0.0f; bool pred = false;
            if (j < NPTS) {
                d = dist3(sx[j], sy[j], sz[j], qx, qy, qz);
                pred = (d <= R1SQ);
            }
            unsigned long long mb = __ballot(pred);
            if (pred) {
                int pos = cn + (int)__popcll(mb & ((1ull << lane) - 1ull));
                if (pos < CANDCAP) { knd[wid][pos] = d; kni[wid][pos] = j; }
            }
            cn += (int)__popcll(mb);
        }
        if (cn > CANDCAP) cn = CANDCAP;  // P(λ≈14 Poisson > 128) ~ 1e-68
        float fmx[5];
#pragma unroll
        for (int f = 0; f < 5; ++f) fmx[f] = -1e30f;
        for (int t = lane; t < cn; t += 64) {
            float d = knd[wid][t]; int j = kni[wid][t];
            bool valid = true;
            if (cn > KNN) {
                int rank = 0;
                for (int u = 0; u < cn; ++u) {
                    float du = knd[wid][u]; int iu = kni[wid][u];
                    rank += (du < d || (du == d && iu < j)) ? 1 : 0;
                }
                valid = rank < KNN;   // replicates top_k stability (ties -> lower idx)
            }
            if (valid) {
                float rx = (sx[j] - qx) * INVR1;
                float ry = (sy[j] - qy) * INVR1;
                float rz = (sz[j] - qz) * INVR1;
#pragma unroll
                for (int f = 0; f < 5; ++f) {
                    float h = fmaf(rx, rw1[f], fmaf(ry, rw1[5 + f], fmaf(rz, rw1[10 + f], rb1[f])));
                    fmx[f] = fmaxf(fmx[f], fmaxf(h, 0.0f));
                }
            }
        }
#pragma unroll
        for (int f = 0; f < 5; ++f) {
            float mx = wave_fmax(fmx[f]);
            if (lane == 0) f1s[s][f] = mx;
        }
    }
    __syncthreads();

    // ---- knn2 + MLP2 -> f2 (one wave per sample2) ----
    for (int s = wid; s < M2C; s += NW) {
        float qx2 = s2x[s], qy2 = s2y[s], qz2 = s2z[s];
        int cn = 0;
#pragma unroll
        for (int c = 0; c < 2; ++c) {
            int j = c * 64 + lane;
            float d = 0.0f; bool pred = false;
            if (j < M1C) {
                d = dist3(smpx[j], smpy[j], smpz[j], qx2, qy2, qz2);
                pred = (d <= R2SQ);
            }
            unsigned long long mb = __ballot(pred);
            if (pred) {
                int pos = cn + (int)__popcll(mb & ((1ull << lane) - 1ull));
                knd[wid][pos] = d; kni[wid][pos] = j;   // cn<=100<CANDCAP
            }
            cn += (int)__popcll(mb);
        }
        float hmx[25];
#pragma unroll
        for (int f = 0; f < 25; ++f) hmx[f] = -1e30f;
        for (int t = lane; t < cn; t += 64) {
            float d = knd[wid][t]; int j = kni[wid][t];
            bool valid = true;
            if (cn > KNN) {
                int rank = 0;
                for (int u = 0; u < cn; ++u) {
                    float du = knd[wid][u]; int iu = kni[wid][u];
                    rank += (du < d || (du == d && iu < j)) ? 1 : 0;
                }
                valid = rank < KNN;
            }
            if (valid) {
                float in8[8];
                in8[0] = smpx[j] - qx2; in8[1] = smpy[j] - qy2; in8[2] = smpz[j] - qz2;
#pragma unroll
                for (int f = 0; f < 5; ++f) in8[3 + f] = f1s[j][f];
#pragma unroll
                for (int f = 0; f < 25; ++f) {
                    float h = b2s[f];
#pragma unroll
                    for (int i = 0; i < 8; ++i) h = fmaf(in8[i], w2s[i * 25 + f], h);
                    hmx[f] = fmaxf(hmx[f], fmaxf(h, 0.0f));
                }
            }
        }
#pragma unroll
        for (int f = 0; f < 25; ++f) {
            float mx = wave_fmax(hmx[f]);
            if (lane == 0) f2s[s][f] = mx;
        }
    }
    __syncthreads();

    // ---- MLP3 + max-pool -> latent (45) ----
    if (wid == 0 && lane < 45) {
        float lm = -1e30f;
        for (int r = 0; r < M2C; ++r) {
            float h = b3s[lane];
            h = fmaf(s2x[r] * 0.5f, w3s[0 * 45 + lane], h);
            h = fmaf(s2y[r] * 0.5f, w3s[1 * 45 + lane], h);
            h = fmaf(s2z[r] * 0.5f, w3s[2 * 45 + lane], h);
#pragma unroll
            for (int i = 0; i < 25; ++i) h = fmaf(f2s[r][i], w3s[(3 + i) * 45 + lane], h);
            lm = fmaxf(lm, fmaxf(h, 0.0f));
        }
        latent[lane] = lm;
    }
    __syncthreads();

    // ---- decoder stage 1: latent @ D1 + bD1 -> (5, 28) ----
    for (int t = tid; t < 140; t += TPB) {
        float acc = bD1[t];
        for (int i = 0; i < 45; i++) acc = fmaf(latent[i], D1[i * 140 + t], acc);
        int r = t / 28, c = t % 28;
        if (c < 3) decv[r][c] = acc;
        else cfs[r][c - 3] = fmaxf(acc, 0.0f);
    }
    __syncthreads();

    // ---- decoder stage 2: cf @ D2 + bD2 -> (100, 8) ----
    for (int t = tid; t < 800; t += TPB) {
        int r = t / 160, c = t % 160;
        float acc = bD2[c];
        for (int i = 0; i < 25; i++) acc = fmaf(cfs[r][i], D2[i * 160 + c], acc);
        int g = r * 20 + c / 8, c8 = c % 8;
        if (c8 < 3) dec2s[g][c8] = acc;
        else cf2s[g][c8 - 3] = fmaxf(acc, 0.0f);
    }
    __syncthreads();

    // ---- decoder stage 3 + compose output ----
    float* outb = out + (size_t)b * (NPTS * 3);
    for (int t = tid; t < NPTS * 3; t += TPB) {
        int n = t / 3, c = t % 3;
        int g = n / 20;
        int m = n / 400;
        int r60 = (n % 20) * 3 + c;
        float acc = bD3[r60];
        for (int i = 0; i < 5; i++) acc = fmaf(cf2s[g][i], D3[i * 60 + r60], acc);
        // out = ((dec*R3 + dec2)*R2 + dec3)*R1, R2 = 1
        float val = ((decv[m][c] * 2.0f + dec2s[g][c]) + acc) * 0.3f;
        outb[t] = val;
    }
}

extern "C" void kernel_launch(void* const* d_in, const int* in_sizes, int n_in,
                              void* d_out, int out_size, void* d_ws, size_t ws_size,
                              hipStream_t stream) {
    const float* P   = (const float*)d_in[0];
    const float* W1  = (const float*)d_in[1];
    const float* b1  = (const float*)d_in[2];
    const float* W2  = (const float*)d_in[3];
    const float* b2  = (const float*)d_in[4];
    const float* W3  = (const float*)d_in[5];
    const float* b3  = (const float*)d_in[6];
    const float* D1  = (const float*)d_in[7];
    const float* bD1 = (const float*)d_in[8];
    const float* D2  = (const float*)d_in[9];
    const float* bD2 = (const float*)d_in[10];
    const float* D3  = (const float*)d_in[11];
    const float* bD3 = (const float*)d_in[12];
    float* out = (float*)d_out;
    float* ws = (float*)d_ws;

    int B = in_sizes[0] / (NPTS * 3);
    hipLaunchKernelGGL(kernelA, dim3(B), dim3(TPBA), 0, stream, P, ws);
    hipLaunchKernelGGL(kernelBC, dim3(B), dim3(TPB), 0, stream,
                       P, W1, b1, W2, b2, W3, b3, D1, bD1, D2, bD2, D3, bD3, ws, out);
}

// Round 6
// 236.463 us; speedup vs baseline: 1.0451x; 1.0035x over previous
//
#include <hip/hip_runtime.h>

#define NPTS 2000
#define M1C 100
#define M2C 5
#define KNN 20
#define CANDCAP 128

// workspace layout (float words), per cloud stride CSTR:
#define CSTR 820
#define OF_SMPX 0
#define OF_SMPY 100
#define OF_SMPZ 200
#define OF_S2   300   // x[300..304] y[305..309] z[310..314]
#define OF_F1   320   // [s*5+f], 500 floats

typedef float v2f __attribute__((ext_vector_type(2)));

// Bitwise-exact squared distance matching numpy fp32 sequential sum:
// ((dx*dx + dy*dy) + dz*dz), no FMA contraction.
__device__ __forceinline__ float dist3(float px, float py, float pz,
                                       float qx, float qy, float qz) {
#pragma clang fp contract(off)
    float dx = px - qx, dy = py - qy, dz = pz - qz;
    return dx * dx + dy * dy + dz * dz;
}

// Packed pair variant: identical per-component op sequence (sub, mul, add, add)
// so each lane/component is bitwise identical to dist3.
__device__ __forceinline__ v2f dist3p(v2f px, v2f py, v2f pz, v2f q0, v2f q1, v2f q2) {
#pragma clang fp contract(off)
    v2f dx = px - q0, dy = py - q1, dz = pz - q2;
    v2f sx = dx * dx;
    v2f sy = dy * dy;
    v2f sz = dz * dz;
    return (sx + sy) + sz;
}

// Fused wave64 (value,index) argmax, min-index tie-break, DPP chain.
#define ARGMAX_STEP(ctrl, rm)                                                        \
    do {                                                                             \
        float ov = __int_as_float(__builtin_amdgcn_update_dpp(                       \
            (int)0xff800000, __float_as_int(v), ctrl, rm, 0xf, false));              \
        int oi = __builtin_amdgcn_update_dpp(0x7fffffff, i, ctrl, rm, 0xf, false);   \
        bool take = (ov > v) || (ov == v && oi < i);                                 \
        v = take ? ov : v;                                                           \
        i = take ? oi : i;                                                           \
    } while (0)

__device__ __forceinline__ void wave_argmax(float& v, int& i) {
    ARGMAX_STEP(0x111, 0xf);
    ARGMAX_STEP(0x112, 0xf);
    ARGMAX_STEP(0x114, 0xf);
    ARGMAX_STEP(0x118, 0xf);
    ARGMAX_STEP(0x142, 0xa);
    ARGMAX_STEP(0x143, 0xc);
    v = __int_as_float(__builtin_amdgcn_readlane(__float_as_int(v), 63));
    i = __builtin_amdgcn_readlane(i, 63);
}

#define FMAX_STEP(ctrl, rm)                                                          \
    do {                                                                             \
        float _t = __int_as_float(__builtin_amdgcn_update_dpp(                       \
            (int)0xff800000, __float_as_int(x), ctrl, rm, 0xf, false));              \
        x = fmaxf(x, _t);                                                            \
    } while (0)

__device__ __forceinline__ float wave_fmax(float x) {
    FMAX_STEP(0x111, 0xf);
    FMAX_STEP(0x112, 0xf);
    FMAX_STEP(0x114, 0xf);
    FMAX_STEP(0x118, 0xf);
    FMAX_STEP(0x142, 0xa);
    FMAX_STEP(0x143, 0xc);
    return __int_as_float(__builtin_amdgcn_readlane(__float_as_int(x), 63));
}

// ================= Kernel A: single-wave FPS (no barriers) =================
__global__ __launch_bounds__(64) void kernelA(const float* __restrict__ P,
                                              float* __restrict__ ws)
{
    __shared__ float sP[3][NPTS];
    __shared__ float smpx[M1C], smpy[M1C], smpz[M1C];

    const int b = blockIdx.x;
    const int lane = threadIdx.x;
    float* sx = sP[0]; float* sy = sP[1]; float* sz = sP[2];

    const float* Pb = P + (size_t)b * (NPTS * 3);
    const float4* P4 = (const float4*)Pb;
    for (int i = lane; i < (NPTS * 3) / 4; i += 64) {
        float4 f = P4[i];
        int j = 4 * i;
        float v[4] = {f.x, f.y, f.z, f.w};
#pragma unroll
        for (int e = 0; e < 4; ++e) {
            int jj = j + e;
            (&sP[0][0])[(jj % 3) * NPTS + jj / 3] = v[e];
        }
    }
    __syncthreads();

    // 32 chunks/lane, point j = k*64 + lane; pack chunk pairs (2p, 2p+1).
    v2f px[16], py[16], pz[16], mind[16];
#pragma unroll
    for (int p = 0; p < 16; ++p) {
#pragma unroll
        for (int h = 0; h < 2; ++h) {
            int j = (2 * p + h) * 64 + lane;
            bool val = j < NPTS;
            int jc = val ? j : 0;
            px[p][h] = val ? sx[jc] : 1e18f;
            py[p][h] = val ? sy[jc] : 1e18f;
            pz[p][h] = val ? sz[jc] : 1e18f;
            mind[p][h] = val ? 1e10f : -1.0f;
        }
    }

    float qx = sx[0], qy = sy[0], qz = sz[0];
    for (int it = 0; it < M1C; ++it) {
        if (lane == 0) { smpx[it] = qx; smpy[it] = qy; smpz[it] = qz; }
        float bv = -1.0f; int bk = 0x7fffffff;
        v2f q0 = {qx, qx}, q1 = {qy, qy}, q2 = {qz, qz};
#pragma unroll
        for (int p = 0; p < 16; ++p) {
            v2f d = dist3p(px[p], py[p], pz[p], q0, q1, q2);
            v2f m;
            m[0] = fminf(mind[p][0], d[0]);
            m[1] = fminf(mind[p][1], d[1]);
            mind[p] = m;
            if (m[0] > bv) { bv = m[0]; bk = 2 * p; }       // strict >: min-k ties
            if (m[1] > bv) { bv = m[1]; bk = 2 * p + 1; }
        }
        if (it == M1C - 1) break;
        int bi = (bk << 6) + lane;                          // flat index j
        wave_argmax(bv, bi);
        qx = sx[bi]; qy = sy[bi]; qz = sz[bi];              // broadcast ds_read
    }
    __syncthreads();

    size_t cs = (size_t)b * CSTR;
    // copy samples to ws
    for (int t = lane; t < M1C; t += 64) {
        ws[cs + OF_SMPX + t] = smpx[t];
        ws[cs + OF_SMPY + t] = smpy[t];
        ws[cs + OF_SMPZ + t] = smpz[t];
    }
    // FPS2: 5 from 100 (same wave)
    float ax = smpx[lane], ay = smpy[lane], az = smpz[lane];
    bool vb2 = lane < (M1C - 64);
    float bx2 = vb2 ? smpx[lane + 64] : 1e18f;
    float by2 = vb2 ? smpy[lane + 64] : 1e18f;
    float bz2 = vb2 ? smpz[lane + 64] : 1e18f;
    float m2a = 1e10f;
    float m2b = vb2 ? 1e10f : -1.0f;
    int last2 = 0;
    for (int it = 0; it < M2C; ++it) {
        float fx = smpx[last2], fy = smpy[last2], fz = smpz[last2];
        if (lane == 0) {
            ws[cs + OF_S2 + it] = fx;
            ws[cs + OF_S2 + 5 + it] = fy;
            ws[cs + OF_S2 + 10 + it] = fz;
        }
        m2a = fminf(m2a, dist3(ax, ay, az, fx, fy, fz));
        m2b = fminf(m2b, dist3(bx2, by2, bz2, fx, fy, fz));
        float v = m2a; int i = lane;
        if (m2b > v) { v = m2b; i = lane + 64; }
        wave_argmax(v, i);
        last2 = i;
    }
}

// ============== Kernel B: knn1 + MLP1, one wave per (cloud,sample) ==============
__global__ __launch_bounds__(256) void kernelB(const float* __restrict__ P,
                                               const float* __restrict__ W1,
                                               const float* __restrict__ b1,
                                               float* __restrict__ ws)
{
    __shared__ float sP[3][NPTS];
    __shared__ float knd[4][CANDCAP];
    __shared__ int   kni[4][CANDCAP];

    const int tid = threadIdx.x;
    const int lane = tid & 63;
    const int wid = tid >> 6;
    const int cloud = blockIdx.x / 25;
    const int s = (blockIdx.x % 25) * 4 + wid;
    float* sx = sP[0]; float* sy = sP[1]; float* sz = sP[2];
    size_t cs = (size_t)cloud * CSTR;

    const float R1SQ = (float)(0.3 * 0.3);   // f64 product then cast
    const float INVR1 = 1.0f / 0.3f;

    const float* Pb = P + (size_t)cloud * (NPTS * 3);
    const float4* P4 = (const float4*)Pb;
    for (int i = tid; i < (NPTS * 3) / 4; i += 256) {
        float4 f = P4[i];
        int j = 4 * i;
        float v[4] = {f.x, f.y, f.z, f.w};
#pragma unroll
        for (int e = 0; e < 4; ++e) {
            int jj = j + e;
            (&sP[0][0])[(jj % 3) * NPTS + jj / 3] = v[e];
        }
    }
    float rw1[15], rb1[5];
#pragma unroll
    for (int i = 0; i < 15; ++i) rw1[i] = W1[i];
#pragma unroll
    for (int i = 0; i < 5; ++i) rb1[i] = b1[i];
    float qx = ws[cs + OF_SMPX + s];
    float qy = ws[cs + OF_SMPY + s];
    float qz = ws[cs + OF_SMPZ + s];
    __syncthreads();

    int cn = 0;
#pragma unroll 4
    for (int c = 0; c < 32; ++c) {
        int j = c * 64 + lane;
        float d = 0.0f; bool pred = false;
        if (j < NPTS) {
            d = dist3(sx[j], sy[j], sz[j], qx, qy, qz);
            pred = (d <= R1SQ);
        }
        unsigned long long mb = __ballot(pred);
        if (pred) {
            int pos = cn + (int)__popcll(mb & ((1ull << lane) - 1ull));
            if (pos < CANDCAP) { knd[wid][pos] = d; kni[wid][pos] = j; }
        }
        cn += (int)__popcll(mb);
    }
    if (cn > CANDCAP) cn = CANDCAP;  // P(Poisson λ≈14 > 128) ~ 1e-68
    float fmx[5];
#pragma unroll
    for (int f = 0; f < 5; ++f) fmx[f] = -1e30f;
    for (int t = lane; t < cn; t += 64) {
        float d = knd[wid][t]; int j = kni[wid][t];
        bool valid = true;
        if (cn > KNN) {
            int rank = 0;
            for (int u = 0; u < cn; ++u) {
                float du = knd[wid][u]; int iu = kni[wid][u];
                rank += (du < d || (du == d && iu < j)) ? 1 : 0;
            }
            valid = rank < KNN;   // replicates top_k stability (ties -> lower idx)
        }
        if (valid) {
            float rx = (sx[j] - qx) * INVR1;
            float ry = (sy[j] - qy) * INVR1;
            float rz = (sz[j] - qz) * INVR1;
#pragma unroll
            for (int f = 0; f < 5; ++f) {
                float h = fmaf(rx, rw1[f], fmaf(ry, rw1[5 + f], fmaf(rz, rw1[10 + f], rb1[f])));
                fmx[f] = fmaxf(fmx[f], fmaxf(h, 0.0f));
            }
        }
    }
#pragma unroll
    for (int f = 0; f < 5; ++f) fmx[f] = wave_fmax(fmx[f]);
    if (lane == 0) {
#pragma unroll
        for (int f = 0; f < 5; ++f) ws[cs + OF_F1 + s * 5 + f] = fmx[f];
    }
}

// ============== Kernel C: knn2 + MLP2 + MLP3 + decoder ==============
#define TPBC 512
#define NWC 8
__global__ __launch_bounds__(TPBC) void kernelC(
    const float* __restrict__ W2, const float* __restrict__ b2,
    const float* __restrict__ W3, const float* __restrict__ b3,
    const float* __restrict__ D1, const float* __restrict__ bD1,
    const float* __restrict__ D2, const float* __restrict__ bD2,
    const float* __restrict__ D3, const float* __restrict__ bD3,
    const float* __restrict__ ws, float* __restrict__ out)
{
    __shared__ float smpx[M1C], smpy[M1C], smpz[M1C];
    __shared__ float s2x[M2C], s2y[M2C], s2z[M2C];
    __shared__ float f1s[M1C][5];
    __shared__ float f2s[M2C][25];
    __shared__ float latent[45];
    __shared__ float decv[M2C][3];
    __shared__ float cfs[M2C][25];
    __shared__ float dec2s[M1C][3];
    __shared__ float cf2s[M1C][5];
    __shared__ float kn2d[NWC][CANDCAP];
    __shared__ int   kn2i[NWC][CANDCAP];
    __shared__ float w2s[200], b2s[25], w3s[1260], b3s[45];

    const int b = blockIdx.x;
    const int tid = threadIdx.x;
    const int lane = tid & 63;
    const int wid = tid >> 6;
    size_t cs = (size_t)b * CSTR;
    const float R2SQ = 1.0f;

    for (int t = tid; t < M1C; t += TPBC) {
        smpx[t] = ws[cs + OF_SMPX + t];
        smpy[t] = ws[cs + OF_SMPY + t];
        smpz[t] = ws[cs + OF_SMPZ + t];
    }
    for (int t = tid; t < M2C; t += TPBC) {
        s2x[t] = ws[cs + OF_S2 + t];
        s2y[t] = ws[cs + OF_S2 + 5 + t];
        s2z[t] = ws[cs + OF_S2 + 10 + t];
    }
    for (int t = tid; t < M1C * 5; t += TPBC) ((float*)f1s)[t] = ws[cs + OF_F1 + t];
    for (int t = tid; t < 200; t += TPBC) w2s[t] = W2[t];
    for (int t = tid; t < 25; t += TPBC) b2s[t] = b2[t];
    for (int t = tid; t < 1260; t += TPBC) w3s[t] = W3[t];
    for (int t = tid; t < 45; t += TPBC) b3s[t] = b3[t];
    __syncthreads();

    // ---- knn2 + MLP2 -> f2 (one wave per sample2) ----
    for (int s = wid; s < M2C; s += NWC) {
        float qx2 = s2x[s], qy2 = s2y[s], qz2 = s2z[s];
        int cn = 0;
#pragma unroll
        for (int c = 0; c < 2; ++c) {
            int j = c * 64 + lane;
            float d = 0.0f; bool pred = false;
            if (j < M1C) {
                d = dist3(smpx[j], smpy[j], smpz[j], qx2, qy2, qz2);
                pred = (d <= R2SQ);
            }
            unsigned long long mb = __ballot(pred);
            if (pred) {
                int pos = cn + (int)__popcll(mb & ((1ull << lane) - 1ull));
                kn2d[wid][pos] = d; kn2i[wid][pos] = j;   // cn<=100<CANDCAP
            }
            cn += (int)__popcll(mb);
        }
        float hmx[25];
#pragma unroll
        for (int f = 0; f < 25; ++f) hmx[f] = -1e30f;
        for (int t = lane; t < cn; t += 64) {
            float d = kn2d[wid][t]; int j = kn2i[wid][t];
            bool valid = true;
            if (cn > KNN) {
                int rank = 0;
                for (int u = 0; u < cn; ++u) {
                    float du = kn2d[wid][u]; int iu = kn2i[wid][u];
                    rank += (du < d || (du == d && iu < j)) ? 1 : 0;
                }
                valid = rank < KNN;
            }
            if (valid) {
                float in8[8];
                in8[0] = smpx[j] - qx2; in8[1] = smpy[j] - qy2; in8[2] = smpz[j] - qz2;
#pragma unroll
                for (int f = 0; f < 5; ++f) in8[3 + f] = f1s[j][f];
#pragma unroll
                for (int f = 0; f < 25; ++f) {
                    float h = b2s[f];
#pragma unroll
                    for (int i = 0; i < 8; ++i) h = fmaf(in8[i], w2s[i * 25 + f], h);
                    hmx[f] = fmaxf(hmx[f], fmaxf(h, 0.0f));
                }
            }
        }
#pragma unroll
        for (int f = 0; f < 25; ++f) {
            float mx = wave_fmax(hmx[f]);
            if (lane == 0) f2s[s][f] = mx;
        }
    }
    __syncthreads();

    // ---- MLP3 + max-pool -> latent (45) ----
    if (wid == 0 && lane < 45) {
        float lm = -1e30f;
        for (int r = 0; r < M2C; ++r) {
            float h = b3s[lane];
            h = fmaf(s2x[r] * 0.5f, w3s[0 * 45 + lane], h);
            h = fmaf(s2y[r] * 0.5f, w3s[1 * 45 + lane], h);
            h = fmaf(s2z[r] * 0.5f, w3s[2 * 45 + lane], h);
#pragma unroll
            for (int i = 0; i < 25; ++i) h = fmaf(f2s[r][i], w3s[(3 + i) * 45 + lane], h);
            lm = fmaxf(lm, fmaxf(h, 0.0f));
        }
        latent[lane] = lm;
    }
    __syncthreads();

    // ---- decoder stage 1: latent @ D1 + bD1 -> (5, 28) ----
    for (int t = tid; t < 140; t += TPBC) {
        float acc = bD1[t];
        for (int i = 0; i < 45; i++) acc = fmaf(latent[i], D1[i * 140 + t], acc);
        int r = t / 28, c = t % 28;
        if (c < 3) decv[r][c] = acc;
        else cfs[r][c - 3] = fmaxf(acc, 0.0f);
    }
    __syncthreads();

    // ---- decoder stage 2: cf @ D2 + bD2 -> (100, 8) ----
    for (int t = tid; t < 800; t += TPBC) {
        int r = t / 160, c = t % 160;
        float acc = bD2[c];
        for (int i = 0; i < 25; i++) acc = fmaf(cfs[r][i], D2[i * 160 + c], acc);
        int g = r * 20 + c / 8, c8 = c % 8;
        if (c8 < 3) dec2s[g][c8] = acc;
        else cf2s[g][c8 - 3] = fmaxf(acc, 0.0f);
    }
    __syncthreads();

    // ---- decoder stage 3 + compose output ----
    float* outb = out + (size_t)b * (NPTS * 3);
    for (int t = tid; t < NPTS * 3; t += TPBC) {
        int n = t / 3, c = t % 3;
        int g = n / 20;
        int m = n / 400;
        int r60 = (n % 20) * 3 + c;
        float acc = bD3[r60];
        for (int i = 0; i < 5; i++) acc = fmaf(cf2s[g][i], D3[i * 60 + r60], acc);
        // out = ((dec*R3 + dec2)*R2 + dec3)*R1, R2 = 1
        float val = ((decv[m][c] * 2.0f + dec2s[g][c]) + acc) * 0.3f;
        outb[t] = val;
    }
}

extern "C" void kernel_launch(void* const* d_in, const int* in_sizes, int n_in,
                              void* d_out, int out_size, void* d_ws, size_t ws_size,
                              hipStream_t stream) {
    const float* P   = (const float*)d_in[0];
    const float* W1  = (const float*)d_in[1];
    const float* b1  = (const float*)d_in[2];
    const float* W2  = (const float*)d_in[3];
    const float* b2  = (const float*)d_in[4];
    const float* W3  = (const float*)d_in[5];
    const float* b3  = (const float*)d_in[6];
    const float* D1  = (const float*)d_in[7];
    const float* bD1 = (const float*)d_in[8];
    const float* D2  = (const float*)d_in[9];
    const float* bD2 = (const float*)d_in[10];
    const float* D3  = (const float*)d_in[11];
    const float* bD3 = (const float*)d_in[12];
    float* out = (float*)d_out;
    float* ws = (float*)d_ws;

    int B = in_sizes[0] / (NPTS * 3);
    hipLaunchKernelGGL(kernelA, dim3(B), dim3(64), 0, stream, P, ws);
    hipLaunchKernelGGL(kernelB, dim3(B * 25), dim3(256), 0, stream, P, W1, b1, ws);
    hipLaunchKernelGGL(kernelC, dim3(B), dim3(TPBC), 0, stream,
                       W2, b2, W3, b3, D1, bD1, D2, bD2, D3, bD3, ws, out);
}

// Round 7
// 205.195 us; speedup vs baseline: 1.2043x; 1.1524x over previous
//
#include <hip/hip_runtime.h>

#define TPB 512
#define NW 8
#define NPTS 2000
#define M1C 100
#define M2C 5
#define KNN 20
#define CANDCAP 128

// Bitwise-exact squared distance matching numpy fp32 sequential sum:
// ((dx*dx + dy*dy) + dz*dz), no FMA contraction.
__device__ __forceinline__ float dist3(float px, float py, float pz,
                                       float qx, float qy, float qz) {
#pragma clang fp contract(off)
    float dx = px - qx, dy = py - qy, dz = pz - qz;
    return dx * dx + dy * dy + dz * dz;
}

// Fused wave64 (value,index) argmax, min-index tie-break, DPP chain.
#define ARGMAX_STEP(ctrl, rm)                                                        \
    do {                                                                             \
        float ov = __int_as_float(__builtin_amdgcn_update_dpp(                       \
            (int)0xff800000, __float_as_int(v), ctrl, rm, 0xf, false));              \
        int oi = __builtin_amdgcn_update_dpp(0x7fffffff, i, ctrl, rm, 0xf, false);   \
        bool take = (ov > v) || (ov == v && oi < i);                                 \
        v = take ? ov : v;                                                           \
        i = take ? oi : i;                                                           \
    } while (0)

__device__ __forceinline__ void wave_argmax(float& v, int& i) {
    ARGMAX_STEP(0x111, 0xf);
    ARGMAX_STEP(0x112, 0xf);
    ARGMAX_STEP(0x114, 0xf);
    ARGMAX_STEP(0x118, 0xf);
    ARGMAX_STEP(0x142, 0xa);
    ARGMAX_STEP(0x143, 0xc);
    v = __int_as_float(__builtin_amdgcn_readlane(__float_as_int(v), 63));
    i = __builtin_amdgcn_readlane(i, 63);
}

#define FMAX_STEP(ctrl, rm)                                                          \
    do {                                                                             \
        float _t = __int_as_float(__builtin_amdgcn_update_dpp(                       \
            (int)0xff800000, __float_as_int(x), ctrl, rm, 0xf, false));              \
        x = fmaxf(x, _t);                                                            \
    } while (0)

__device__ __forceinline__ float wave_fmax(float x) {
    FMAX_STEP(0x111, 0xf);
    FMAX_STEP(0x112, 0xf);
    FMAX_STEP(0x114, 0xf);
    FMAX_STEP(0x118, 0xf);
    FMAX_STEP(0x142, 0xa);
    FMAX_STEP(0x143, 0xc);
    return __int_as_float(__builtin_amdgcn_readlane(__float_as_int(x), 63));
}

// ============ Fused kernel: FPS producers + knn1/MLP1 consumers + tail ============
__global__ __launch_bounds__(TPB, 2) void fused_kernel(
    const float* __restrict__ P,
    const float* __restrict__ W1, const float* __restrict__ b1,
    const float* __restrict__ W2, const float* __restrict__ b2,
    const float* __restrict__ W3, const float* __restrict__ b3,
    const float* __restrict__ D1, const float* __restrict__ bD1,
    const float* __restrict__ D2, const float* __restrict__ bD2,
    const float* __restrict__ D3, const float* __restrict__ bD3,
    float* __restrict__ out)
{
    __shared__ float sP[3][NPTS];
    __shared__ float smpx[M1C], smpy[M1C], smpz[M1C];
    __shared__ float s2x[M2C], s2y[M2C], s2z[M2C];
    __shared__ float f1s[M1C][5];
    __shared__ float knd[NW][CANDCAP];
    __shared__ int   kni[NW][CANDCAP];
    __shared__ __align__(16) float4 sA[2][4];
    __shared__ __align__(16) float  sZ[2][4];
    __shared__ int flags[4];               // flags[w] = #iterations wave w completed
    __shared__ float f2s[M2C][25];
    __shared__ float latent[45];
    __shared__ float decv[M2C][3];
    __shared__ float cfs[M2C][25];
    __shared__ float dec2s[M1C][3];
    __shared__ float cf2s[M1C][5];
    __shared__ float w2s[200], b2s[25], w3s[1260], b3s[45];

    const int b = blockIdx.x;
    const int tid = threadIdx.x;
    const int lane = tid & 63;
    const int wid = tid >> 6;
    float* sx = sP[0]; float* sy = sP[1]; float* sz = sP[2];

    const float R1SQ = (float)(0.3 * 0.3);   // f64 product then cast
    const float R2SQ = 1.0f;
    const float INVR1 = 1.0f / 0.3f;

    // ---- staging (all 8 waves) ----
    const float* Pb = P + (size_t)b * (NPTS * 3);
    const float4* P4 = (const float4*)Pb;
    for (int i = tid; i < (NPTS * 3) / 4; i += TPB) {
        float4 f = P4[i];
        int j = 4 * i;
        float v[4] = {f.x, f.y, f.z, f.w};
#pragma unroll
        for (int e = 0; e < 4; ++e) {
            int jj = j + e;
            (&sP[0][0])[(jj % 3) * NPTS + jj / 3] = v[e];
        }
    }
    for (int t = tid; t < 200; t += TPB) w2s[t] = W2[t];
    for (int t = tid; t < 25; t += TPB) b2s[t] = b2[t];
    for (int t = tid; t < 1260; t += TPB) w3s[t] = W3[t];
    for (int t = tid; t < 45; t += TPB) b3s[t] = b3[t];
    if (tid < 4) flags[tid] = 0;
    __syncthreads();

    if (wid < 4) {
        // ================= producers: FPS1 (waves 0-3, tid 0..255) =================
        float px[8], py[8], pz[8], mind[8];
#pragma unroll
        for (int k = 0; k < 8; ++k) {
            int j = tid + (k << 8);
            bool v = j < NPTS;
            int jc = v ? j : 0;
            px[k] = v ? sx[jc] : 1e18f;
            py[k] = v ? sy[jc] : 1e18f;
            pz[k] = v ? sz[jc] : 1e18f;
            mind[k] = v ? 1e10f : -1.0f;
        }

        float qx = sx[0], qy = sy[0], qz = sz[0];
        for (int it = 0; it < M1C; ++it) {
            if (tid == 0) { smpx[it] = qx; smpy[it] = qy; smpz[it] = qz; }
            float bv = -1.0f; int bi = 0x7fffffff;
#pragma unroll
            for (int k = 0; k < 8; ++k) {
                float d = dist3(px[k], py[k], pz[k], qx, qy, qz);
                float m = fminf(mind[k], d);
                mind[k] = m;
                if (m > bv) { bv = m; bi = tid + (k << 8); }   // strict >: min-idx ties
            }
            if (it == M1C - 1) {
                // release smp[99] for consumers
                if (lane == 0)
                    __hip_atomic_store(&flags[wid], M1C, __ATOMIC_RELEASE,
                                       __HIP_MEMORY_SCOPE_WORKGROUP);
                break;
            }
            float lv = bv; int li = bi;
            wave_argmax(bv, bi);
            int p = it & 1;
            if (lv == bv && li == bi) {            // unique winner lane per wave
                int k = bi >> 8;
                float cx = px[0], cy = py[0], cz = pz[0];
#pragma unroll
                for (int kk = 1; kk < 8; ++kk) {
                    bool t = (k == kk);
                    cx = t ? px[kk] : cx;
                    cy = t ? py[kk] : cy;
                    cz = t ? pz[kk] : cz;
                }
                sA[p][wid] = make_float4(bv, __int_as_float(bi), cx, cy);
                sZ[p][wid] = cz;
            }
            // release own slot (orders the wave's prior ds_writes)
            if (lane == 0)
                __hip_atomic_store(&flags[wid], it + 1, __ATOMIC_RELEASE,
                                   __HIP_MEMORY_SCOPE_WORKGROUP);
            // spin until all 4 producer waves posted this iteration
            for (;;) {
                int f = 0x7fffffff;
                if (lane < 4)
                    f = __hip_atomic_load(&flags[lane], __ATOMIC_ACQUIRE,
                                          __HIP_MEMORY_SCOPE_WORKGROUP);
                if (__ballot(f >= it + 1) == ~0ull) break;
                __builtin_amdgcn_s_sleep(1);
            }
            float4 a0 = sA[p][0], a1 = sA[p][1], a2 = sA[p][2], a3 = sA[p][3];
            float4 z0 = *(const float4*)&sZ[p][0];
            float cv = a0.x; int ci = __float_as_int(a0.y);
            qx = a0.z; qy = a0.w; qz = z0.x;
#define SEL(aw, zz)                                                                  \
            {                                                                        \
                int ii = __float_as_int(aw.y);                                       \
                bool t = (aw.x > cv) || (aw.x == cv && ii < ci);                     \
                if (t) { cv = aw.x; ci = ii; qx = aw.z; qy = aw.w; qz = zz; }        \
            }
            SEL(a1, z0.y) SEL(a2, z0.z) SEL(a3, z0.w)
#undef SEL
        }

        if (wid == 0) {
            // ---- FPS2: 5 from 100 (single wave, in-LDS smp) ----
            float ax = smpx[lane], ay = smpy[lane], az = smpz[lane];
            bool vb2 = lane < (M1C - 64);
            float bx2 = vb2 ? smpx[lane + 64] : 1e18f;
            float by2 = vb2 ? smpy[lane + 64] : 1e18f;
            float bz2 = vb2 ? smpz[lane + 64] : 1e18f;
            float m2a = 1e10f;
            float m2b = vb2 ? 1e10f : -1.0f;
            int last2 = 0;
            for (int it = 0; it < M2C; ++it) {
                float fx = smpx[last2], fy = smpy[last2], fz = smpz[last2];
                if (lane == 0) { s2x[it] = fx; s2y[it] = fy; s2z[it] = fz; }
                m2a = fminf(m2a, dist3(ax, ay, az, fx, fy, fz));
                m2b = fminf(m2b, dist3(bx2, by2, bz2, fx, fy, fz));
                float v = m2a; int i = lane;
                if (m2b > v) { v = m2b; i = lane + 64; }
                wave_argmax(v, i);
                last2 = i;
            }
        }
    } else {
        // ================= consumers: knn1 + MLP1 (waves 4-7) =================
        float rw1[15], rb1[5];
#pragma unroll
        for (int i = 0; i < 15; ++i) rw1[i] = W1[i];
#pragma unroll
        for (int i = 0; i < 5; ++i) rb1[i] = b1[i];

        for (int s = wid - 4; s < M1C; s += 4) {
            // wait until producer wave 0 has published smp[s]
            while (__hip_atomic_load(&flags[0], __ATOMIC_ACQUIRE,
                                     __HIP_MEMORY_SCOPE_WORKGROUP) <= s)
                __builtin_amdgcn_s_sleep(2);
            float qx = smpx[s], qy = smpy[s], qz = smpz[s];
            int cn = 0;
#pragma unroll 4
            for (int c = 0; c < 32; ++c) {
                int j = c * 64 + lane;
                float d = 0.0f; bool pred = false;
                if (j < NPTS) {
                    d = dist3(sx[j], sy[j], sz[j], qx, qy, qz);
                    pred = (d <= R1SQ);
                }
                unsigned long long mb = __ballot(pred);
                if (pred) {
                    int pos = cn + (int)__popcll(mb & ((1ull << lane) - 1ull));
                    if (pos < CANDCAP) { knd[wid][pos] = d; kni[wid][pos] = j; }
                }
                cn += (int)__popcll(mb);
            }
            if (cn > CANDCAP) cn = CANDCAP;  // P(Poisson λ≈14 > 128) ~ 1e-68
            float fmx[5];
#pragma unroll
            for (int f = 0; f < 5; ++f) fmx[f] = -1e30f;
            for (int t = lane; t < cn; t += 64) {
                float d = knd[wid][t]; int j = kni[wid][t];
                bool valid = true;
                if (cn > KNN) {
                    int rank = 0;
                    for (int u = 0; u < cn; ++u) {
                        float du = knd[wid][u]; int iu = kni[wid][u];
                        rank += (du < d || (du == d && iu < j)) ? 1 : 0;
                    }
                    valid = rank < KNN;   // replicates top_k stability (ties -> lower idx)
                }
                if (valid) {
                    float rx = (sx[j] - qx) * INVR1;
                    float ry = (sy[j] - qy) * INVR1;
                    float rz = (sz[j] - qz) * INVR1;
#pragma unroll
                    for (int f = 0; f < 5; ++f) {
                        float h = fmaf(rx, rw1[f], fmaf(ry, rw1[5 + f], fmaf(rz, rw1[10 + f], rb1[f])));
                        fmx[f] = fmaxf(fmx[f], fmaxf(h, 0.0f));
                    }
                }
            }
#pragma unroll
            for (int f = 0; f < 5; ++f) fmx[f] = wave_fmax(fmx[f]);
            if (lane == 0) {
#pragma unroll
                for (int f = 0; f < 5; ++f) f1s[s][f] = fmx[f];
            }
        }
    }
    __syncthreads();   // all 8 waves reach exactly once

    // ================= tail: knn2 + MLP2, MLP3, decoder =================
    for (int s = wid; s < M2C; s += NW) {
        float qx2 = s2x[s], qy2 = s2y[s], qz2 = s2z[s];
        int cn = 0;
#pragma unroll
        for (int c = 0; c < 2; ++c) {
            int j = c * 64 + lane;
            float d = 0.0f; bool pred = false;
            if (j < M1C) {
                d = dist3(smpx[j], smpy[j], smpz[j], qx2, qy2, qz2);
                pred = (d <= R2SQ);
            }
            unsigned long long mb = __ballot(pred);
            if (pred) {
                int pos = cn + (int)__popcll(mb & ((1ull << lane) - 1ull));
                knd[wid][pos] = d; kni[wid][pos] = j;   // cn<=100<CANDCAP
            }
            cn += (int)__popcll(mb);
        }
        float hmx[25];
#pragma unroll
        for (int f = 0; f < 25; ++f) hmx[f] = -1e30f;
        for (int t = lane; t < cn; t += 64) {
            float d = knd[wid][t]; int j = kni[wid][t];
            bool valid = true;
            if (cn > KNN) {
                int rank = 0;
                for (int u = 0; u < cn; ++u) {
                    float du = knd[wid][u]; int iu = kni[wid][u];
                    rank += (du < d || (du == d && iu < j)) ? 1 : 0;
                }
                valid = rank < KNN;
            }
            if (valid) {
                float in8[8];
                in8[0] = smpx[j] - qx2; in8[1] = smpy[j] - qy2; in8[2] = smpz[j] - qz2;
#pragma unroll
                for (int f = 0; f < 5; ++f) in8[3 + f] = f1s[j][f];
#pragma unroll
                for (int f = 0; f < 25; ++f) {
                    float h = b2s[f];
#pragma unroll
                    for (int i = 0; i < 8; ++i) h = fmaf(in8[i], w2s[i * 25 + f], h);
                    hmx[f] = fmaxf(hmx[f], fmaxf(h, 0.0f));
                }
            }
        }
#pragma unroll
        for (int f = 0; f < 25; ++f) {
            float mx = wave_fmax(hmx[f]);
            if (lane == 0) f2s[s][f] = mx;
        }
    }
    __syncthreads();

    // ---- MLP3 + max-pool -> latent (45) ----
    if (wid == 0 && lane < 45) {
        float lm = -1e30f;
        for (int r = 0; r < M2C; ++r) {
            float h = b3s[lane];
            h = fmaf(s2x[r] * 0.5f, w3s[0 * 45 + lane], h);
            h = fmaf(s2y[r] * 0.5f, w3s[1 * 45 + lane], h);
            h = fmaf(s2z[r] * 0.5f, w3s[2 * 45 + lane], h);
#pragma unroll
            for (int i = 0; i < 25; ++i) h = fmaf(f2s[r][i], w3s[(3 + i) * 45 + lane], h);
            lm = fmaxf(lm, fmaxf(h, 0.0f));
        }
        latent[lane] = lm;
    }
    __syncthreads();

    // ---- decoder stage 1: latent @ D1 + bD1 -> (5, 28) ----
    for (int t = tid; t < 140; t += TPB) {
        float acc = bD1[t];
        for (int i = 0; i < 45; i++) acc = fmaf(latent[i], D1[i * 140 + t], acc);
        int r = t / 28, c = t % 28;
        if (c < 3) decv[r][c] = acc;
        else cfs[r][c - 3] = fmaxf(acc, 0.0f);
    }
    __syncthreads();

    // ---- decoder stage 2: cf @ D2 + bD2 -> (100, 8) ----
    for (int t = tid; t < 800; t += TPB) {
        int r = t / 160, c = t % 160;
        float acc = bD2[c];
        for (int i = 0; i < 25; i++) acc = fmaf(cfs[r][i], D2[i * 160 + c], acc);
        int g = r * 20 + c / 8, c8 = c % 8;
        if (c8 < 3) dec2s[g][c8] = acc;
        else cf2s[g][c8 - 3] = fmaxf(acc, 0.0f);
    }
    __syncthreads();

    // ---- decoder stage 3 + compose output ----
    float* outb = out + (size_t)b * (NPTS * 3);
    for (int t = tid; t < NPTS * 3; t += TPB) {
        int n = t / 3, c = t % 3;
        int g = n / 20;
        int m = n / 400;
        int r60 = (n % 20) * 3 + c;
        float acc = bD3[r60];
        for (int i = 0; i < 5; i++) acc = fmaf(cf2s[g][i], D3[i * 60 + r60], acc);
        // out = ((dec*R3 + dec2)*R2 + dec3)*R1, R2 = 1
        float val = ((decv[m][c] * 2.0f + dec2s[g][c]) + acc) * 0.3f;
        outb[t] = val;
    }
}

extern "C" void kernel_launch(void* const* d_in, const int* in_sizes, int n_in,
                              void* d_out, int out_size, void* d_ws, size_t ws_size,
                              hipStream_t stream) {
    const float* P   = (const float*)d_in[0];
    const float* W1  = (const float*)d_in[1];
    const float* b1  = (const float*)d_in[2];
    const float* W2  = (const float*)d_in[3];
    const float* b2  = (const float*)d_in[4];
    const float* W3  = (const float*)d_in[5];
    const float* b3  = (const float*)d_in[6];
    const float* D1  = (const float*)d_in[7];
    const float* bD1 = (const float*)d_in[8];
    const float* D2  = (const float*)d_in[9];
    const float* bD2 = (const float*)d_in[10];
    const float* D3  = (const float*)d_in[11];
    const float* bD3 = (const float*)d_in[12];
    float* out = (float*)d_out;

    int B = in_sizes[0] / (NPTS * 3);
    hipLaunchKernelGGL(fused_kernel, dim3(B), dim3(TPB), 0, stream,
                       P, W1, b1, W2, b2, W3, b3, D1, bD1, D2, bD2, D3, bD3, out);
}

// Round 8
// 202.435 us; speedup vs baseline: 1.2207x; 1.0136x over previous
//
#include <hip/hip_runtime.h>

#define TPB 512
#define NW 8
#define NPTS 2000
#define M1C 100
#define M2C 5
#define KNN 20
#define CANDCAP 128

// Bitwise-exact squared distance matching numpy fp32 sequential sum:
// ((dx*dx + dy*dy) + dz*dz), no FMA contraction.
__device__ __forceinline__ float dist3(float px, float py, float pz,
                                       float qx, float qy, float qz) {
#pragma clang fp contract(off)
    float dx = px - qx, dy = py - qy, dz = pz - qz;
    return dx * dx + dy * dy + dz * dz;
}

// Fused wave64 (value,index) argmax, min-index tie-break, DPP chain.
#define ARGMAX_STEP(ctrl, rm)                                                        \
    do {                                                                             \
        float ov = __int_as_float(__builtin_amdgcn_update_dpp(                       \
            (int)0xff800000, __float_as_int(v), ctrl, rm, 0xf, false));              \
        int oi = __builtin_amdgcn_update_dpp(0x7fffffff, i, ctrl, rm, 0xf, false);   \
        bool take = (ov > v) || (ov == v && oi < i);                                 \
        v = take ? ov : v;                                                           \
        i = take ? oi : i;                                                           \
    } while (0)

__device__ __forceinline__ void wave_argmax(float& v, int& i) {
    ARGMAX_STEP(0x111, 0xf);
    ARGMAX_STEP(0x112, 0xf);
    ARGMAX_STEP(0x114, 0xf);
    ARGMAX_STEP(0x118, 0xf);
    ARGMAX_STEP(0x142, 0xa);
    ARGMAX_STEP(0x143, 0xc);
    v = __int_as_float(__builtin_amdgcn_readlane(__float_as_int(v), 63));
    i = __builtin_amdgcn_readlane(i, 63);
}

#define FMAX_STEP(ctrl, rm)                                                          \
    do {                                                                             \
        float _t = __int_as_float(__builtin_amdgcn_update_dpp(                       \
            (int)0xff800000, __float_as_int(x), ctrl, rm, 0xf, false));              \
        x = fmaxf(x, _t);                                                            \
    } while (0)

__device__ __forceinline__ float wave_fmax(float x) {
    FMAX_STEP(0x111, 0xf);
    FMAX_STEP(0x112, 0xf);
    FMAX_STEP(0x114, 0xf);
    FMAX_STEP(0x118, 0xf);
    FMAX_STEP(0x142, 0xa);
    FMAX_STEP(0x143, 0xc);
    return __int_as_float(__builtin_amdgcn_readlane(__float_as_int(x), 63));
}

// ============ Fused kernel: FPS producers + knn1/MLP1 consumers + tail ============
__global__ __launch_bounds__(TPB, 2) void fused_kernel(
    const float* __restrict__ P,
    const float* __restrict__ W1, const float* __restrict__ b1,
    const float* __restrict__ W2, const float* __restrict__ b2,
    const float* __restrict__ W3, const float* __restrict__ b3,
    const float* __restrict__ D1, const float* __restrict__ bD1,
    const float* __restrict__ D2, const float* __restrict__ bD2,
    const float* __restrict__ D3, const float* __restrict__ bD3,
    float* __restrict__ out)
{
    __shared__ __align__(16) float4 sP4[NPTS];   // {x,y,z,unused}
    __shared__ float smpx[M1C], smpy[M1C], smpz[M1C];
    __shared__ float s2x[M2C], s2y[M2C], s2z[M2C];
    __shared__ float f1s[M1C][5];
    __shared__ float knd[NW][CANDCAP];
    __shared__ int   kni[NW][CANDCAP];
    __shared__ __align__(16) float4 sA[2][4];
    __shared__ __align__(16) float  sZ[2][4];
    __shared__ int flags[4];               // flags[w] = #iterations wave w completed
    __shared__ float f2s[M2C][25];
    __shared__ float latent[45];
    __shared__ float decv[M2C][3];
    __shared__ float cfs[M2C][25];
    __shared__ float dec2s[M1C][3];
    __shared__ float cf2s[M1C][5];
    __shared__ float w2s[200], b2s[25], w3s[1260], b3s[45];

    const int b = blockIdx.x;
    const int tid = threadIdx.x;
    const int lane = tid & 63;
    const int wid = tid >> 6;

    const float R1SQ = (float)(0.3 * 0.3);   // f64 product then cast
    const float R2SQ = 1.0f;
    const float INVR1 = 1.0f / 0.3f;

    // ---- staging (all 8 waves): xyz-packed float4 layout ----
    const float* Pb = P + (size_t)b * (NPTS * 3);
    const float4* P4 = (const float4*)Pb;
    for (int i = tid; i < (NPTS * 3) / 4; i += TPB) {
        float4 f = P4[i];
        int base = 4 * i;
        float v[4] = {f.x, f.y, f.z, f.w};
#pragma unroll
        for (int e = 0; e < 4; ++e) {
            int fi = base + e;
            int pt = fi / 3, c = fi - 3 * pt;
            ((float*)&sP4[pt])[c] = v[e];
        }
    }
    for (int t = tid; t < 200; t += TPB) w2s[t] = W2[t];
    for (int t = tid; t < 25; t += TPB) b2s[t] = b2[t];
    for (int t = tid; t < 1260; t += TPB) w3s[t] = W3[t];
    for (int t = tid; t < 45; t += TPB) b3s[t] = b3[t];
    if (tid < 4) flags[tid] = 0;
    __syncthreads();

    if (wid < 4) {
        // ================= producers: FPS1 (waves 0-3, tid 0..255) =================
        __builtin_amdgcn_s_setprio(3);
        float px[8], py[8], pz[8], mind[8];
#pragma unroll
        for (int k = 0; k < 8; ++k) {
            int j = tid + (k << 8);
            bool v = j < NPTS;
            float4 p = v ? sP4[j] : make_float4(1e18f, 1e18f, 1e18f, 0.0f);
            px[k] = p.x; py[k] = p.y; pz[k] = p.z;
            mind[k] = v ? 1e10f : -1.0f;
        }

        float qx = sP4[0].x, qy = sP4[0].y, qz = sP4[0].z;
        for (int it = 0; it < M1C; ++it) {
            if (tid == 0) { smpx[it] = qx; smpy[it] = qy; smpz[it] = qz; }
            float m[8];
#pragma unroll
            for (int k = 0; k < 8; ++k) {
                float d = dist3(px[k], py[k], pz[k], qx, qy, qz);
                m[k] = fminf(mind[k], d);
                mind[k] = m[k];
            }
            // tree argmax over 8 chunks; strict > keeps lowest chunk on ties
            float va = m[0]; int ka = 0; if (m[1] > va) { va = m[1]; ka = 1; }
            float vb = m[2]; int kb = 2; if (m[3] > vb) { vb = m[3]; kb = 3; }
            float vc = m[4]; int kc = 4; if (m[5] > vc) { vc = m[5]; kc = 5; }
            float vd = m[6]; int kd = 6; if (m[7] > vd) { vd = m[7]; kd = 7; }
            if (vb > va) { va = vb; ka = kb; }
            if (vd > vc) { vc = vd; kc = kd; }
            if (vc > va) { va = vc; ka = kc; }
            float bv = va; int bi = tid + (ka << 8);
            if (it == M1C - 1) {
                if (lane == 0)
                    __hip_atomic_store(&flags[wid], M1C, __ATOMIC_RELEASE,
                                       __HIP_MEMORY_SCOPE_WORKGROUP);
                break;
            }
            float lv = bv; int li = bi;
            wave_argmax(bv, bi);
            int p = it & 1;
            if (lv == bv && li == bi) {            // unique winner lane per wave
                int k = bi >> 8;
                float cx = px[0], cy = py[0], cz = pz[0];
#pragma unroll
                for (int kk = 1; kk < 8; ++kk) {
                    bool t = (k == kk);
                    cx = t ? px[kk] : cx;
                    cy = t ? py[kk] : cy;
                    cz = t ? pz[kk] : cz;
                }
                sA[p][wid] = make_float4(bv, __int_as_float(bi), cx, cy);
                sZ[p][wid] = cz;
            }
            if (lane == 0)
                __hip_atomic_store(&flags[wid], it + 1, __ATOMIC_RELEASE,
                                   __HIP_MEMORY_SCOPE_WORKGROUP);
            // tight spin (priority 3): wait all 4 producer waves posted
            for (;;) {
                int f = 0x7fffffff;
                if (lane < 4)
                    f = __hip_atomic_load(&flags[lane], __ATOMIC_ACQUIRE,
                                          __HIP_MEMORY_SCOPE_WORKGROUP);
                if (__ballot(f >= it + 1) == ~0ull) break;
            }
            float4 a0 = sA[p][0], a1 = sA[p][1], a2 = sA[p][2], a3 = sA[p][3];
            float4 z0 = *(const float4*)&sZ[p][0];
            // tree combine, min-index ties
            float cv0 = a0.x; int ci0 = __float_as_int(a0.y);
            float x0 = a0.z, y0 = a0.w, zz0 = z0.x;
            {
                int ii = __float_as_int(a1.y);
                bool t = (a1.x > cv0) || (a1.x == cv0 && ii < ci0);
                if (t) { cv0 = a1.x; ci0 = ii; x0 = a1.z; y0 = a1.w; zz0 = z0.y; }
            }
            float cv1 = a2.x; int ci1 = __float_as_int(a2.y);
            float x1 = a2.z, y1 = a2.w, zz1 = z0.z;
            {
                int ii = __float_as_int(a3.y);
                bool t = (a3.x > cv1) || (a3.x == cv1 && ii < ci1);
                if (t) { cv1 = a3.x; ci1 = ii; x1 = a3.z; y1 = a3.w; zz1 = z0.w; }
            }
            bool t = (cv1 > cv0) || (cv1 == cv0 && ci1 < ci0);
            qx = t ? x1 : x0; qy = t ? y1 : y0; qz = t ? zz1 : zz0;
        }

        if (wid == 0) {
            // ---- FPS2: 5 from 100 (single wave, in-LDS smp) ----
            float ax = smpx[lane], ay = smpy[lane], az = smpz[lane];
            bool vb2 = lane < (M1C - 64);
            float bx2 = vb2 ? smpx[lane + 64] : 1e18f;
            float by2 = vb2 ? smpy[lane + 64] : 1e18f;
            float bz2 = vb2 ? smpz[lane + 64] : 1e18f;
            float m2a = 1e10f;
            float m2b = vb2 ? 1e10f : -1.0f;
            int last2 = 0;
            for (int it = 0; it < M2C; ++it) {
                float fx = smpx[last2], fy = smpy[last2], fz = smpz[last2];
                if (lane == 0) { s2x[it] = fx; s2y[it] = fy; s2z[it] = fz; }
                m2a = fminf(m2a, dist3(ax, ay, az, fx, fy, fz));
                m2b = fminf(m2b, dist3(bx2, by2, bz2, fx, fy, fz));
                float v = m2a; int i = lane;
                if (m2b > v) { v = m2b; i = lane + 64; }
                wave_argmax(v, i);
                last2 = i;
            }
        }
        __builtin_amdgcn_s_setprio(0);
    } else {
        // ================= consumers: knn1 + MLP1 (waves 4-7) =================
        __builtin_amdgcn_s_setprio(0);
        float rw1[15], rb1[5];
#pragma unroll
        for (int i = 0; i < 15; ++i) rw1[i] = W1[i];
#pragma unroll
        for (int i = 0; i < 5; ++i) rb1[i] = b1[i];

        for (int s = wid - 4; s < M1C; s += 4) {
            // wait until producer wave 0 has published smp[s]
            while (__hip_atomic_load(&flags[0], __ATOMIC_ACQUIRE,
                                     __HIP_MEMORY_SCOPE_WORKGROUP) <= s)
                __builtin_amdgcn_s_sleep(2);
            float qx = smpx[s], qy = smpy[s], qz = smpz[s];
            int cn = 0;
#pragma unroll 4
            for (int c = 0; c < 32; ++c) {
                int j = c * 64 + lane;
                float d = 0.0f; bool pred = false;
                if (j < NPTS) {
                    float4 p = sP4[j];
                    d = dist3(p.x, p.y, p.z, qx, qy, qz);
                    pred = (d <= R1SQ);
                }
                unsigned long long mb = __ballot(pred);
                if (pred) {
                    int pos = cn + (int)__popcll(mb & ((1ull << lane) - 1ull));
                    if (pos < CANDCAP) { knd[wid][pos] = d; kni[wid][pos] = j; }
                }
                cn += (int)__popcll(mb);
            }
            if (cn > CANDCAP) cn = CANDCAP;  // P(Poisson λ≈14 > 128) ~ 1e-68
            float fmx[5];
#pragma unroll
            for (int f = 0; f < 5; ++f) fmx[f] = -1e30f;
            for (int t = lane; t < cn; t += 64) {
                float d = knd[wid][t]; int j = kni[wid][t];
                bool valid = true;
                if (cn > KNN) {
                    int rank = 0;
                    for (int u = 0; u < cn; ++u) {
                        float du = knd[wid][u]; int iu = kni[wid][u];
                        rank += (du < d || (du == d && iu < j)) ? 1 : 0;
                    }
                    valid = rank < KNN;   // replicates top_k stability (ties -> lower idx)
                }
                if (valid) {
                    float4 p = sP4[j];
                    float rx = (p.x - qx) * INVR1;
                    float ry = (p.y - qy) * INVR1;
                    float rz = (p.z - qz) * INVR1;
#pragma unroll
                    for (int f = 0; f < 5; ++f) {
                        float h = fmaf(rx, rw1[f], fmaf(ry, rw1[5 + f], fmaf(rz, rw1[10 + f], rb1[f])));
                        fmx[f] = fmaxf(fmx[f], fmaxf(h, 0.0f));
                    }
                }
            }
#pragma unroll
            for (int f = 0; f < 5; ++f) fmx[f] = wave_fmax(fmx[f]);
            if (lane == 0) {
#pragma unroll
                for (int f = 0; f < 5; ++f) f1s[s][f] = fmx[f];
            }
        }
    }
    __syncthreads();   // all 8 waves reach exactly once

    // ================= tail: knn2 + MLP2, MLP3, decoder =================
    for (int s = wid; s < M2C; s += NW) {
        float qx2 = s2x[s], qy2 = s2y[s], qz2 = s2z[s];
        int cn = 0;
#pragma unroll
        for (int c = 0; c < 2; ++c) {
            int j = c * 64 + lane;
            float d = 0.0f; bool pred = false;
            if (j < M1C) {
                d = dist3(smpx[j], smpy[j], smpz[j], qx2, qy2, qz2);
                pred = (d <= R2SQ);
            }
            unsigned long long mb = __ballot(pred);
            if (pred) {
                int pos = cn + (int)__popcll(mb & ((1ull << lane) - 1ull));
                knd[wid][pos] = d; kni[wid][pos] = j;   // cn<=100<CANDCAP
            }
            cn += (int)__popcll(mb);
        }
        float hmx[25];
#pragma unroll
        for (int f = 0; f < 25; ++f) hmx[f] = -1e30f;
        for (int t = lane; t < cn; t += 64) {
            float d = knd[wid][t]; int j = kni[wid][t];
            bool valid = true;
            if (cn > KNN) {
                int rank = 0;
                for (int u = 0; u < cn; ++u) {
                    float du = knd[wid][u]; int iu = kni[wid][u];
                    rank += (du < d || (du == d && iu < j)) ? 1 : 0;
                }
                valid = rank < KNN;
            }
            if (valid) {
                float in8[8];
                in8[0] = smpx[j] - qx2; in8[1] = smpy[j] - qy2; in8[2] = smpz[j] - qz2;
#pragma unroll
                for (int f = 0; f < 5; ++f) in8[3 + f] = f1s[j][f];
#pragma unroll
                for (int f = 0; f < 25; ++f) {
                    float h = b2s[f];
#pragma unroll
                    for (int i = 0; i < 8; ++i) h = fmaf(in8[i], w2s[i * 25 + f], h);
                    hmx[f] = fmaxf(hmx[f], fmaxf(h, 0.0f));
                }
            }
        }
#pragma unroll
        for (int f = 0; f < 25; ++f) {
            float mx = wave_fmax(hmx[f]);
            if (lane == 0) f2s[s][f] = mx;
        }
    }
    __syncthreads();

    // ---- MLP3 + max-pool -> latent (45) ----
    if (wid == 0 && lane < 45) {
        float lm = -1e30f;
        for (int r = 0; r < M2C; ++r) {
            float h = b3s[lane];
            h = fmaf(s2x[r] * 0.5f, w3s[0 * 45 + lane], h);
            h = fmaf(s2y[r] * 0.5f, w3s[1 * 45 + lane], h);
            h = fmaf(s2z[r] * 0.5f, w3s[2 * 45 + lane], h);
#pragma unroll
            for (int i = 0; i < 25; ++i) h = fmaf(f2s[r][i], w3s[(3 + i) * 45 + lane], h);
            lm = fmaxf(lm, fmaxf(h, 0.0f));
        }
        latent[lane] = lm;
    }
    __syncthreads();

    // ---- decoder stage 1: latent @ D1 + bD1 -> (5, 28) ----
    for (int t = tid; t < 140; t += TPB) {
        float acc = bD1[t];
        for (int i = 0; i < 45; i++) acc = fmaf(latent[i], D1[i * 140 + t], acc);
        int r = t / 28, c = t % 28;
        if (c < 3) decv[r][c] = acc;
        else cfs[r][c - 3] = fmaxf(acc, 0.0f);
    }
    __syncthreads();

    // ---- decoder stage 2: cf @ D2 + bD2 -> (100, 8) ----
    for (int t = tid; t < 800; t += TPB) {
        int r = t / 160, c = t % 160;
        float acc = bD2[c];
        for (int i = 0; i < 25; i++) acc = fmaf(cfs[r][i], D2[i * 160 + c], acc);
        int g = r * 20 + c / 8, c8 = c % 8;
        if (c8 < 3) dec2s[g][c8] = acc;
        else cf2s[g][c8 - 3] = fmaxf(acc, 0.0f);
    }
    __syncthreads();

    // ---- decoder stage 3 + compose output ----
    float* outb = out + (size_t)b * (NPTS * 3);
    for (int t = tid; t < NPTS * 3; t += TPB) {
        int n = t / 3, c = t % 3;
        int g = n / 20;
        int m = n / 400;
        int r60 = (n % 20) * 3 + c;
        float acc = bD3[r60];
        for (int i = 0; i < 5; i++) acc = fmaf(cf2s[g][i], D3[i * 60 + r60], acc);
        // out = ((dec*R3 + dec2)*R2 + dec3)*R1, R2 = 1
        float val = ((decv[m][c] * 2.0f + dec2s[g][c]) + acc) * 0.3f;
        outb[t] = val;
    }
}

extern "C" void kernel_launch(void* const* d_in, const int* in_sizes, int n_in,
                              void* d_out, int out_size, void* d_ws, size_t ws_size,
                              hipStream_t stream) {
    const float* P   = (const float*)d_in[0];
    const float* W1  = (const float*)d_in[1];
    const float* b1  = (const float*)d_in[2];
    const float* W2  = (const float*)d_in[3];
    const float* b2  = (const float*)d_in[4];
    const float* W3  = (const float*)d_in[5];
    const float* b3  = (const float*)d_in[6];
    const float* D1  = (const float*)d_in[7];
    const float* bD1 = (const float*)d_in[8];
    const float* D2  = (const float*)d_in[9];
    const float* bD2 = (const float*)d_in[10];
    const float* D3  = (const float*)d_in[11];
    const float* bD3 = (const float*)d_in[12];
    float* out = (float*)d_out;

    int B = in_sizes[0] / (NPTS * 3);
    hipLaunchKernelGGL(fused_kernel, dim3(B), dim3(TPB), 0, stream,
                       P, W1, b1, W2, b2, W3, b3, D1, bD1, D2, bD2, D3, bD3, out);
}